// Round 1
// baseline (388.464 us; speedup 1.0000x reference)
//
#include <hip/hip_runtime.h>

// ---------------------------------------------------------------------------
// DotProductAttention: B=4, S=2048, H*D=E=1024, causal, out-proj W^T + bias.
// Round 1: correctness-first bf16-MFMA flash attention + m97-style GEMM.
//   ws layout: Kbf 16MB | Vt 16MB | Abf 16MB | Wbf 2MB  (needs >= 50MB)
// ---------------------------------------------------------------------------

typedef __attribute__((ext_vector_type(8))) short bf16x8;
typedef __attribute__((ext_vector_type(4))) float floatx4;

#define MFMA16(a, b, c) __builtin_amdgcn_mfma_f32_16x16x32_bf16((a), (b), (c), 0, 0, 0)

#define B_ 4
#define S_ 2048
#define E_ 1024

static __device__ __forceinline__ unsigned short f2bf(float f) {
  unsigned int u = __float_as_uint(f);
  u += 0x7FFFu + ((u >> 16) & 1u);   // RNE
  return (unsigned short)(u >> 16);
}

// ---------------- fp32 -> bf16 elementwise (vectorized) ----------------
__global__ void cvt_bf16_kernel(const float* __restrict__ in,
                                unsigned short* __restrict__ out, int n4) {
  int i = blockIdx.x * blockDim.x + threadIdx.x;
  int stride = gridDim.x * blockDim.x;
  for (; i < n4; i += stride) {
    float4 v = ((const float4*)in)[i];
    ushort4 o;
    o.x = f2bf(v.x); o.y = f2bf(v.y); o.z = f2bf(v.z); o.w = f2bf(v.w);
    ((ushort4*)out)[i] = o;
  }
}

// ---------------- V [B][S][E] f32 -> Vt [B][E][S] bf16 ----------------
__global__ void transpose_v_kernel(const float* __restrict__ V,
                                   unsigned short* __restrict__ Vt) {
  __shared__ float tile[32][33];
  int bid = blockIdx.x;
  int eb = (bid & 31) * 32;
  int sb = ((bid >> 5) & 63) * 32;
  int b  = bid >> 11;
  int tx = threadIdx.x & 31, ty = threadIdx.x >> 5;  // ty 0..7
  const float* src = V + ((size_t)(b * S_ + sb)) * E_ + eb;
#pragma unroll
  for (int i = 0; i < 4; ++i) {
    int sl = ty + i * 8;
    tile[sl][tx] = src[(size_t)sl * E_ + tx];
  }
  __syncthreads();
  unsigned short* dst = Vt + ((size_t)(b * E_ + eb)) * S_ + sb;
#pragma unroll
  for (int i = 0; i < 4; ++i) {
    int el = ty + i * 8;
    dst[(size_t)el * S_ + tx] = f2bf(tile[tx][el]);
  }
}

// ---------------- flash attention ----------------
// grid = B * (S/32) = 256 WGs, 256 threads (4 waves).
// Wave w owns E-slice [w*256, w*256+256) of Q (registers) and O (acc regs).
// Swapped QK^T: S_tile[k][q] = mfma(A=K, B=Qscaled); cross-wave LDS reduce;
// online softmax by 8-lane row groups; PV from Vt with P staged in LDS.
__global__ __launch_bounds__(256, 1) void attn_kernel(
    const float* __restrict__ Q,
    const unsigned short* __restrict__ Kbf,
    const unsigned short* __restrict__ Vt,
    unsigned short* __restrict__ Abf) {
  __shared__ float sred[4][4][256];        // [wave][kf*2+qf][swizzled lane*4+reg]
  __shared__ unsigned short ptile[32][40]; // pad 40 -> 80B rows, 16B aligned
  __shared__ float scaleL[32];
  __shared__ float lfin[32];

  const int wg = blockIdx.x;
  const int b  = wg >> 6;
  const int ib = wg & 63;
  const int qb0 = ib * 32;
  const int tid = threadIdx.x;
  const int w = tid >> 6, l = tid & 63;
  const int l15 = l & 15, l4 = l >> 4;
  const int e0 = w * 256;

  // Q fragments (B operand), scaled by E^-0.5 = 1/32, cvt to bf16.
  bf16x8 qfrag[2][8];
#pragma unroll
  for (int qf = 0; qf < 2; ++qf) {
    const float* qp = Q + ((size_t)(b * S_ + qb0 + qf * 16 + l15)) * E_ + e0 + l4 * 8;
#pragma unroll
    for (int ks = 0; ks < 8; ++ks) {
      float4 x0 = *(const float4*)(qp + ks * 32);
      float4 x1 = *(const float4*)(qp + ks * 32 + 4);
      bf16x8 f;
      f[0] = f2bf(x0.x * 0.03125f); f[1] = f2bf(x0.y * 0.03125f);
      f[2] = f2bf(x0.z * 0.03125f); f[3] = f2bf(x0.w * 0.03125f);
      f[4] = f2bf(x1.x * 0.03125f); f[5] = f2bf(x1.y * 0.03125f);
      f[6] = f2bf(x1.z * 0.03125f); f[7] = f2bf(x1.w * 0.03125f);
      qfrag[qf][ks] = f;
    }
  }

  floatx4 oacc[2][16];
#pragma unroll
  for (int m = 0; m < 2; ++m)
#pragma unroll
    for (int n = 0; n < 16; ++n) oacc[m][n] = (floatx4)0.0f;

  float m_run = -1e30f, l_run = 0.0f;

  // softmax-role constants: thread t handles row q_sm, keys kb4..kb4+3.
  const int q_sm = tid >> 3;
  const int kb4  = (tid & 7) * 4;
  const int g_sm = (kb4 >> 2) & 3;                    // producing lane>>4
  const int lps  = ((((g_sm << 4) | (q_sm & 15)) ^ g_sm)) * 4;
  const int region_sm = (kb4 >> 4) * 2 + (q_sm >> 4); // kf*2+qf
  const int lsw = (l ^ l4) * 4;                       // write-side swizzle

  for (int j = 0; j <= ib; ++j) {
    const int kg0 = j * 32;
    // ---- partial S over this wave's E-slice
    floatx4 sacc[2][2];
#pragma unroll
    for (int a = 0; a < 2; ++a)
#pragma unroll
      for (int c = 0; c < 2; ++c) sacc[a][c] = (floatx4)0.0f;
    const unsigned short* kp = Kbf + ((size_t)(b * S_ + kg0)) * E_ + e0 + l4 * 8;
#pragma unroll
    for (int ks = 0; ks < 8; ++ks) {
#pragma unroll
      for (int kf = 0; kf < 2; ++kf) {
        bf16x8 kfr = *(const bf16x8*)(kp + (size_t)(kf * 16 + l15) * E_ + ks * 32);
        sacc[kf][0] = MFMA16(kfr, qfrag[0][ks], sacc[kf][0]);
        sacc[kf][1] = MFMA16(kfr, qfrag[1][ks], sacc[kf][1]);
      }
    }
#pragma unroll
    for (int kf = 0; kf < 2; ++kf)
#pragma unroll
      for (int qf = 0; qf < 2; ++qf)
        *(floatx4*)&sred[w][kf * 2 + qf][lsw] = sacc[kf][qf];
    __syncthreads();

    // ---- softmax stage (all 256 threads)
    floatx4 s = *(const floatx4*)&sred[0][region_sm][lps];
    s += *(const floatx4*)&sred[1][region_sm][lps];
    s += *(const floatx4*)&sred[2][region_sm][lps];
    s += *(const floatx4*)&sred[3][region_sm][lps];
    const int qg = qb0 + q_sm;
    const int kg = kg0 + kb4;
#pragma unroll
    for (int i = 0; i < 4; ++i)
      if (kg + i > qg) s[i] = -1e30f;   // causal mask
    float mx = fmaxf(fmaxf(s[0], s[1]), fmaxf(s[2], s[3]));
    mx = fmaxf(mx, __shfl_xor(mx, 1));
    mx = fmaxf(mx, __shfl_xor(mx, 2));
    mx = fmaxf(mx, __shfl_xor(mx, 4));
    const float mnew = fmaxf(m_run, mx);
    float p0 = __expf(s[0] - mnew), p1 = __expf(s[1] - mnew);
    float p2 = __expf(s[2] - mnew), p3 = __expf(s[3] - mnew);
    float rs = (p0 + p1) + (p2 + p3);
    rs += __shfl_xor(rs, 1);
    rs += __shfl_xor(rs, 2);
    rs += __shfl_xor(rs, 4);
    const float corr = __expf(m_run - mnew);
    l_run = l_run * corr + rs;
    m_run = mnew;
    if ((tid & 7) == 0) scaleL[q_sm] = corr;
    ushort4 pw; pw.x = f2bf(p0); pw.y = f2bf(p1); pw.z = f2bf(p2); pw.w = f2bf(p3);
    *(ushort4*)&ptile[q_sm][kb4] = pw;
    __syncthreads();

    // ---- rescale O, then PV
    float sc0[4], sc1[4];
#pragma unroll
    for (int r = 0; r < 4; ++r) {
      sc0[r] = scaleL[l4 * 4 + r];
      sc1[r] = scaleL[16 + l4 * 4 + r];
    }
#pragma unroll
    for (int n = 0; n < 16; ++n)
#pragma unroll
      for (int r = 0; r < 4; ++r) {
        oacc[0][n][r] *= sc0[r];
        oacc[1][n][r] *= sc1[r];
      }
    bf16x8 pfr0 = *(const bf16x8*)&ptile[l15][l4 * 8];
    bf16x8 pfr1 = *(const bf16x8*)&ptile[16 + l15][l4 * 8];
    const unsigned short* vp = Vt + ((size_t)(b * E_ + e0)) * S_ + kg0 + l4 * 8;
#pragma unroll
    for (int n = 0; n < 16; ++n) {
      bf16x8 vfr = *(const bf16x8*)(vp + (size_t)(n * 16 + l15) * S_);
      oacc[0][n] = MFMA16(pfr0, vfr, oacc[0][n]);
      oacc[1][n] = MFMA16(pfr1, vfr, oacc[1][n]);
    }
    __syncthreads();
  }

  if ((tid & 7) == 0) lfin[q_sm] = l_run;
  __syncthreads();
  float inv0[4], inv1[4];
#pragma unroll
  for (int r = 0; r < 4; ++r) {
    inv0[r] = 1.0f / lfin[l4 * 4 + r];
    inv1[r] = 1.0f / lfin[16 + l4 * 4 + r];
  }
  unsigned short* op = Abf + ((size_t)(b * S_ + qb0)) * E_ + e0;
#pragma unroll
  for (int mf = 0; mf < 2; ++mf)
#pragma unroll
    for (int n = 0; n < 16; ++n)
#pragma unroll
      for (int r = 0; r < 4; ++r) {
        int row = mf * 16 + l4 * 4 + r;
        float v = oacc[mf][n][r] * (mf ? inv1[r] : inv0[r]);
        op[(size_t)row * E_ + n * 16 + l15] = f2bf(v);
      }
}

// ---------------- out-proj GEMM: C[M=8192][N=1024] = A[M][K] * Bw[N][K]^T + bias
// m97 structure: 128x128 tile, BK=32, 4 waves (2x2 of 64x64), global_load_lds w16.
__global__ __launch_bounds__(256, 2) void gemm_bt_kernel(
    const unsigned short* __restrict__ A,
    const unsigned short* __restrict__ Bw,
    const float* __restrict__ bias,
    float* __restrict__ C) {
  const int N = E_, K = E_;
  __shared__ unsigned short At[128 * 32];
  __shared__ unsigned short Bt[128 * 32];
  const int tid = threadIdx.x;
  const int w = tid >> 6, l = tid & 63;
  const int l15 = l & 15, l4 = l >> 4;
  const int wr = w >> 1, wc = w & 1;
  const int bm = (blockIdx.x >> 3) * 128;
  const int bn = (blockIdx.x & 7) * 128;

  floatx4 acc[4][4];
#pragma unroll
  for (int m = 0; m < 4; ++m)
#pragma unroll
    for (int n = 0; n < 4; ++n) acc[m][n] = (floatx4)0.0f;

  for (int k0 = 0; k0 < K; k0 += 32) {
#pragma unroll
    for (int i = 0; i < 2; ++i) {
      int c = i * 256 + w * 64 + l;      // 16B chunk id, row-major [128][32]
      int row = c >> 2, col = (c & 3) * 8;
      __builtin_amdgcn_global_load_lds(
          (const __attribute__((address_space(1))) unsigned int*)(A + (size_t)(bm + row) * K + k0 + col),
          (__attribute__((address_space(3))) unsigned int*)(At + (size_t)(i * 256 + w * 64) * 8),
          16, 0, 0);
      __builtin_amdgcn_global_load_lds(
          (const __attribute__((address_space(1))) unsigned int*)(Bw + (size_t)(bn + row) * K + k0 + col),
          (__attribute__((address_space(3))) unsigned int*)(Bt + (size_t)(i * 256 + w * 64) * 8),
          16, 0, 0);
    }
    __syncthreads();
    bf16x8 af[4], bfv[4];
#pragma unroll
    for (int mf = 0; mf < 4; ++mf)
      af[mf] = *(const bf16x8*)&At[(wr * 64 + mf * 16 + l15) * 32 + l4 * 8];
#pragma unroll
    for (int nf = 0; nf < 4; ++nf)
      bfv[nf] = *(const bf16x8*)&Bt[(wc * 64 + nf * 16 + l15) * 32 + l4 * 8];
#pragma unroll
    for (int mf = 0; mf < 4; ++mf)
#pragma unroll
      for (int nf = 0; nf < 4; ++nf)
        acc[mf][nf] = MFMA16(af[mf], bfv[nf], acc[mf][nf]);
    __syncthreads();
  }

  float bv[4];
#pragma unroll
  for (int nf = 0; nf < 4; ++nf) bv[nf] = bias[bn + wc * 64 + nf * 16 + l15];
#pragma unroll
  for (int mf = 0; mf < 4; ++mf)
#pragma unroll
    for (int nf = 0; nf < 4; ++nf)
#pragma unroll
      for (int r = 0; r < 4; ++r) {
        int row = bm + wr * 64 + mf * 16 + l4 * 4 + r;
        int col = bn + wc * 64 + nf * 16 + l15;
        C[(size_t)row * N + col] = acc[mf][nf][r] + bv[nf];
      }
}

extern "C" void kernel_launch(void* const* d_in, const int* in_sizes, int n_in,
                              void* d_out, int out_size, void* d_ws, size_t ws_size,
                              hipStream_t stream) {
  const float* Q    = (const float*)d_in[0];
  const float* Kf   = (const float*)d_in[1];
  const float* V    = (const float*)d_in[2];
  // d_in[3] qkv_proj unused; d_in[4] attn_mask is tril(ones) -> causal, not read.
  const float* W    = (const float*)d_in[5];
  const float* bias = (const float*)d_in[6];
  float* out = (float*)d_out;

  char* ws = (char*)d_ws;
  unsigned short* Kbf = (unsigned short*)(ws);
  unsigned short* Vt  = (unsigned short*)(ws + (size_t)(16u << 20));
  unsigned short* Abf = (unsigned short*)(ws + (size_t)(32u << 20));
  unsigned short* Wbf = (unsigned short*)(ws + (size_t)(48u << 20));

  cvt_bf16_kernel<<<2048, 256, 0, stream>>>(Kf, Kbf, (B_ * S_ * E_) / 4);
  cvt_bf16_kernel<<<512, 256, 0, stream>>>(W, Wbf, (E_ * E_) / 4);
  transpose_v_kernel<<<B_ * (S_ / 32) * (E_ / 32), 256, 0, stream>>>(V, Vt);
  attn_kernel<<<B_ * (S_ / 32), 256, 0, stream>>>(Q, Kbf, Vt, Abf);
  gemm_bt_kernel<<<(B_ * S_ / 128) * (E_ / 128), 256, 0, stream>>>(Abf, Wbf, bias, out);
}